// Round 21
// baseline (53.774 us; speedup 1.0000x reference)
//
#include <hip/hip_runtime.h>
#include <hip/hip_bf16.h>

typedef __attribute__((ext_vector_type(8))) __bf16 bf16x8;
typedef __attribute__((ext_vector_type(4))) float f32x4;

__device__ __forceinline__ f32x4 mfma16(bf16x8 a, bf16x8 b, f32x4 c) {
    return __builtin_amdgcn_mfma_f32_16x16x32_bf16(a, b, c, 0, 0, 0);
}

__device__ __forceinline__ unsigned short f2bf(float x) {
    union { float f; unsigned int u; } cv; cv.f = x;
    unsigned int r = cv.u + 0x7FFFu + ((cv.u >> 16) & 1u);
    return (unsigned short)(r >> 16);
}

__device__ __forceinline__ unsigned pack2(float a, float b) {
    return (unsigned)f2bf(a) | ((unsigned)f2bf(b) << 16);
}

__device__ __forceinline__ unsigned pk2(float a, float b) {
    float2 f2; f2.x = a; f2.y = b;
    __hip_bfloat162 h = __float22bfloat162_rn(f2);
    return *(unsigned*)&h;
}

__device__ __forceinline__ float fast_exp2(float x) {
    float r;
    asm("v_exp_f32 %0, %1" : "=v"(r) : "v"(x));
    return r;
}

// swap a[32:63] <-> b[0:31]   (operands must be distinct SSA values: R6 bug)
__device__ __forceinline__ void permswap32(unsigned &a, unsigned &b) {
    asm("v_permlane32_swap_b32 %0, %1" : "+v"(a), "+v"(b));
}
__device__ __forceinline__ void permswap16(unsigned &a, unsigned &b) {
    asm("v_permlane16_swap_b32 %0, %1" : "+v"(a), "+v"(b));
}

__device__ __forceinline__ void gload_lds16(const void* g, void* l) {
    __builtin_amdgcn_global_load_lds(
        (const __attribute__((address_space(1))) unsigned int*)g,
        (__attribute__((address_space(3))) unsigned int*)l, 16, 0, 0);
}

// ---------------- Kernel 1: fused weight-norm + q/k transpose ---------------
// Outputs K-CHUNKED layouts for coalesced GEMM staging:
//   qT/kT: [B][K/32][S][32]   Wn: [proj][K/32][512][32]
__global__ __launch_bounds__(256) void prep_kernel(
    const float* __restrict__ q, const float* __restrict__ k,
    const float* __restrict__ Wq_v, const float* __restrict__ Wq_g,
    const float* __restrict__ Wk_v, const float* __restrict__ Wk_g,
    const float* __restrict__ Wv_v, const float* __restrict__ Wv_g,
    unsigned short* __restrict__ qT, unsigned short* __restrict__ kT,
    unsigned short* __restrict__ Wn)
{
    __shared__ float tile[32][33];
    int z = blockIdx.z;
    int t = threadIdx.x;
    if (z == 16) {
        int w = t >> 6, lane = t & 63;
        int idx = (blockIdx.y * 32 + blockIdx.x) * 4 + w;   // 0..1535
        int proj = idx >> 9, o = idx & 511;
        const float* v = (proj == 0 ? Wq_v : proj == 1 ? Wk_v : Wv_v) + (size_t)o * 384;
        const float* g = (proj == 0 ? Wq_g : proj == 1 ? Wk_g : Wv_g);
        float vals[6];
        float ss = 0.f;
#pragma unroll
        for (int i = 0; i < 6; ++i) { vals[i] = v[lane + i * 64]; ss += vals[i] * vals[i]; }
#pragma unroll
        for (int off = 1; off < 64; off <<= 1) ss += __shfl_xor(ss, off, 64);
        float scale = g[o] * rsqrtf(ss);
        unsigned short* dst = Wn + (size_t)proj * 512 * 384;
#pragma unroll
        for (int i = 0; i < 6; ++i) {
            int c = lane + i * 64;
            dst[((size_t)(c >> 5) * 512 + o) * 32 + (c & 31)] = f2bf(vals[i] * scale);
        }
        return;
    }
    int tx = t & 31, ty = t >> 5;
    const float* src = (z < 8 ? q : k) + (size_t)(z & 7) * 384 * 1024;
    unsigned short* dst = (z < 8 ? qT : kT) + (size_t)(z & 7) * 1024 * 384;
    int c0 = blockIdx.y * 32, s0 = blockIdx.x * 32;
#pragma unroll
    for (int j = 0; j < 4; ++j)
        tile[ty + j * 8][tx] = src[(size_t)(c0 + ty + j * 8) * 1024 + s0 + tx];
    __syncthreads();
    int cp = tx & 15;
    int chunk = c0 >> 5;
#pragma unroll
    for (int j = 0; j < 2; ++j) {
        int ss = ty + (tx >> 4) * 8 + j * 16;
        *(unsigned*)&dst[((size_t)chunk * 1024 + s0 + ss) * 32 + 2 * cp] =
            pk2(tile[2 * cp][ss], tile[2 * cp + 1][ss]);
    }
}

// ---------------- Kernel 2: projection GEMM (R14 version, best measured) ----
// K-chunked inputs -> fully coalesced staging (4 x 1KB gloads per wave/step),
// double-buffered. proj==0 (Q) output PRE-SCALED by 1/sqrt(64)*log2(e).
__global__ __launch_bounds__(256) void proj_gemm(
    const unsigned short* __restrict__ qT, const unsigned short* __restrict__ kT,
    const unsigned short* __restrict__ Wn,
    const float* __restrict__ bq, const float* __restrict__ bk, const float* __restrict__ bv,
    unsigned short* __restrict__ Qp, unsigned short* __restrict__ Kp,
    unsigned short* __restrict__ Vt)
{
    __shared__ __align__(16) unsigned short pool[4][128 * 32];   // Asm[2] | Bsm[2]
    int zb = blockIdx.z; int proj = zb >> 3, b = zb & 7;
    const unsigned short* A = (proj == 0 ? qT : kT) + (size_t)b * 1024 * 384;
    const unsigned short* Bw = Wn + (size_t)proj * 512 * 384;
    const float* bias = proj == 0 ? bq : (proj == 1 ? bk : bv);
    int m0 = blockIdx.x * 128, n0 = blockIdx.y * 128;
    int t = threadIdx.x, w = t >> 6, lane = t & 63;
    int fr = lane & 15, fq = lane >> 4;
    int wm = (w >> 1) * 64, wn = (w & 1) * 64;

    f32x4 acc[4][4];
#pragma unroll
    for (int i = 0; i < 4; ++i)
#pragma unroll
        for (int j = 0; j < 4; ++j) acc[i][j] = (f32x4){0.f, 0.f, 0.f, 0.f};

    auto stageAB = [&](int k0, int bufi) {
        int ch = k0 >> 5;
        const unsigned short* ab = A + ((size_t)ch * 1024 + m0) * 32 + w * 1024 + lane * 8;
        const unsigned short* bb = Bw + ((size_t)ch * 512 + n0) * 32 + w * 1024 + lane * 8;
        gload_lds16(ab, &pool[bufi][w * 1024]);
        gload_lds16(ab + 512, &pool[bufi][w * 1024 + 512]);
        gload_lds16(bb, &pool[2 + bufi][w * 1024]);
        gload_lds16(bb + 512, &pool[2 + bufi][w * 1024 + 512]);
    };

    stageAB(0, 0);
    for (int ks = 0; ks < 12; ++ks) {
        if (ks < 11) {
            stageAB((ks + 1) * 32, (ks + 1) & 1);
            asm volatile("s_waitcnt vmcnt(4)" ::: "memory");
        } else {
            asm volatile("s_waitcnt vmcnt(0)" ::: "memory");
        }
        __builtin_amdgcn_s_barrier();
        int bi = ks & 1;
        bf16x8 af[4], bfr[4];
#pragma unroll
        for (int i = 0; i < 4; ++i)
            af[i] = *(const bf16x8*)&pool[bi][(wm + i * 16 + fr) * 32 + fq * 8];
#pragma unroll
        for (int i = 0; i < 4; ++i)
            bfr[i] = *(const bf16x8*)&pool[2 + bi][(wn + i * 16 + fr) * 32 + fq * 8];
#pragma unroll
        for (int mi = 0; mi < 4; ++mi)
#pragma unroll
            for (int ni = 0; ni < 4; ++ni)
                acc[mi][ni] = mfma16(af[mi], bfr[ni], acc[mi][ni]);
        asm volatile("s_waitcnt lgkmcnt(0)" ::: "memory");
        __builtin_amdgcn_s_barrier();
    }

    if (proj == 2) {
#pragma unroll
        for (int mi = 0; mi < 4; ++mi)
#pragma unroll
            for (int ni = 0; ni < 4; ++ni) {
                int c = n0 + wn + ni * 16 + fr;
                int s0 = m0 + wm + mi * 16 + fq * 4;
                float bc = bias[c];
                unsigned lo = pack2(acc[mi][ni][0] + bc, acc[mi][ni][1] + bc);
                unsigned hi = pack2(acc[mi][ni][2] + bc, acc[mi][ni][3] + bc);
                uint2 u; u.x = lo; u.y = hi;
                *(uint2*)&Vt[(((size_t)b * 512 + c) * 1024 + s0)] = u;
            }
    } else {
        unsigned short* Out = (proj == 0 ? Qp : Kp) + (size_t)b * 1024 * 512;
        float vscale = (proj == 0) ? 0.18033688011112043f : 1.0f;
        const int STR = 72;
        unsigned short* scr = &pool[0][0] + w * 2304;
#pragma unroll
        for (int p = 0; p < 2; ++p) {
#pragma unroll
            for (int mh = 0; mh < 2; ++mh) {
                int mi = p * 2 + mh;
#pragma unroll
                for (int ni = 0; ni < 4; ++ni) {
                    int c = n0 + wn + ni * 16 + fr;
                    float bc = bias[c];
#pragma unroll
                    for (int r = 0; r < 4; ++r)
                        scr[(mh * 16 + fq * 4 + r) * STR + ni * 16 + fr] =
                            f2bf((acc[mi][ni][r] + bc) * vscale);
                }
            }
            asm volatile("s_waitcnt lgkmcnt(0)" ::: "memory");
            int sp = lane >> 1, ch = (lane & 1) * 32;
            int s = m0 + wm + p * 32 + sp;
#pragma unroll
            for (int kk = 0; kk < 4; ++kk) {
                bf16x8 v = *(const bf16x8*)&scr[sp * STR + ch + 8 * kk];
                *(bf16x8*)&Out[(size_t)s * 512 + n0 + wn + ch + 8 * kk] = v;
            }
            asm volatile("s_waitcnt lgkmcnt(0)" ::: "memory");
        }
    }
}

// ---------------- Kernel 3: flash attention, KVBLK=64, single-buffer --------
// LDS 16KB -> 6 blocks/CU (24 waves/CU). T5 setprio around MFMA clusters:
// 6 independent blocks/CU at uncorrelated phases give the scheduler role
// diversity (m191 regime), so prio-boosting MFMA-phase waves can pay.
__global__ __launch_bounds__(256, 6) void attn_kernel(
    const unsigned short* __restrict__ Qp, const unsigned short* __restrict__ Kp,
    const unsigned short* __restrict__ Vt, float* __restrict__ out)
{
    __shared__ __align__(16) unsigned short Kl[64 * 64];   // [key][c], swizzled
    __shared__ __align__(16) unsigned short Vl[64 * 64];   // [d][key], swizzled
    int y = blockIdx.y;
    int qtile = y < 4 ? y : (y < 8 ? 19 - y : (y < 12 ? 15 - y : y - 4));
    int bh = blockIdx.x, b = bh >> 3, h = bh & 7;
    int tid = threadIdx.x, w = tid >> 6, lane = tid & 63;
    int fr = lane & 15, fq = lane >> 4;
    const unsigned short* Qb = Qp + ((size_t)b * 1024) * 512 + h * 64;
    const unsigned short* Kb = Kp + ((size_t)b * 1024) * 512 + h * 64;
    const unsigned short* VTb = Vt + ((size_t)b * 512 + h * 64) * 1024;
    int f3 = fr & 7;
    int sw = 8 * ((lane & 7) ^ (lane >> 3));      // stage pre-swizzle (shorts)

    union { unsigned u[4]; bf16x8 v; } ones;
#pragma unroll
    for (int i = 0; i < 4; ++i) ones.u[i] = 0x3F803F80u;   // bf16 1.0 pairs

    auto stage = [&](int kt) {
        int kbase = kt * 64;
#pragma unroll
        for (int i = 0; i < 2; ++i) {
            int r0 = w * 16 + i * 8;
            gload_lds16(Kb + (size_t)(kbase + r0 + (lane >> 3)) * 512 + sw,
                        &Kl[r0 * 64]);
        }
#pragma unroll
        for (int i = 0; i < 2; ++i) {
            int d0 = w * 16 + i * 8;
            gload_lds16(VTb + (size_t)(d0 + (lane >> 3)) * 1024 + kbase + sw,
                        &Vl[d0 * 64]);
        }
    };

    int row0 = qtile * 64 + w * 16;
    int nt = qtile + 1;                 // 64-key units
    int qrow = row0 + fr;

    bf16x8 qf0 = *(const bf16x8*)(Qb + (size_t)(row0 + fr) * 512 + fq * 8);
    bf16x8 qf1 = *(const bf16x8*)(Qb + (size_t)(row0 + fr) * 512 + 32 + fq * 8);

    f32x4 Ot[4];
#pragma unroll
    for (int f = 0; f < 4; ++f) Ot[f] = (f32x4){0.f, 0.f, 0.f, 0.f};
    float M = -128.f, L = 0.f;

    for (int kt = 0; kt < nt; ++kt) {
        int kbase = kt * 64;
        stage(kt);
        asm volatile("s_waitcnt vmcnt(0)" ::: "memory");
        __builtin_amdgcn_s_barrier();

        // ---- QK^T (swapped): S[kg] = D[key=kg*16+fq*4+r][q=fr], pre-scaled
        f32x4 S[4];
        __builtin_amdgcn_s_setprio(1);
#pragma unroll
        for (int kg = 0; kg < 4; ++kg) {
            bf16x8 k0 = *(const bf16x8*)&Kl[(kg * 16 + fr) * 64 + ((fq ^ f3) * 8)];
            bf16x8 k1 = *(const bf16x8*)&Kl[(kg * 16 + fr) * 64 + (((4 + fq) ^ f3) * 8)];
            S[kg] = mfma16(k0, qf0, (f32x4){0.f, 0.f, 0.f, 0.f});
            S[kg] = mfma16(k1, qf1, S[kg]);
        }
        __builtin_amdgcn_s_setprio(0);

        // ---- mask + online softmax (log2 domain, defer-max THR=8)
        float vmax = -3e38f;
#pragma unroll
        for (int kg = 0; kg < 4; ++kg)
#pragma unroll
            for (int r = 0; r < 4; ++r) {
                int key = kbase + kg * 16 + fq * 4 + r;
                float sv = (key < qrow) ? S[kg][r] : -3e38f;
                S[kg][r] = sv;
                vmax = fmaxf(vmax, sv);
            }
        vmax = fmaxf(vmax, __shfl_xor(vmax, 16, 64));
        vmax = fmaxf(vmax, __shfl_xor(vmax, 32, 64));
        if (__any(vmax > M + 8.f)) {
            float Mn = fmaxf(M, vmax);
            float al = fast_exp2(M - Mn);
            L *= al;
            M = Mn;
#pragma unroll
            for (int f = 0; f < 4; ++f) {
                Ot[f][0] *= al; Ot[f][1] *= al; Ot[f][2] *= al; Ot[f][3] *= al;
            }
        }
#pragma unroll
        for (int kg = 0; kg < 4; ++kg)
#pragma unroll
            for (int r = 0; r < 4; ++r)
                S[kg][r] = fast_exp2(S[kg][r] - M);   // masked -> 0

        // ---- in-register P -> B-frags (2 frags of 32 keys)
        bf16x8 pb[2];
#pragma unroll
        for (int m = 0; m < 2; ++m) {
            unsigned A0 = pk2(S[2 * m][0], S[2 * m][1]);
            unsigned A1 = pk2(S[2 * m][2], S[2 * m][3]);
            unsigned B0 = pk2(S[2 * m + 1][0], S[2 * m + 1][1]);
            unsigned B1 = pk2(S[2 * m + 1][2], S[2 * m + 1][3]);
            permswap32(A0, B0); permswap16(A0, B0);
            permswap32(A1, B1); permswap16(A1, B1);
            union { unsigned u[4]; bf16x8 v; } pu;
            pu.u[0] = A0; pu.u[1] = A1; pu.u[2] = B0; pu.u[3] = B1;
            pb[m] = pu.v;
        }

        // ---- denominator + PV (one prio-boosted MFMA cluster)
        __builtin_amdgcn_s_setprio(1);
        f32x4 accS = (f32x4){0.f, 0.f, 0.f, 0.f};
        accS = mfma16(ones.v, pb[0], accS);
        accS = mfma16(ones.v, pb[1], accS);
#pragma unroll
        for (int m = 0; m < 2; ++m)
#pragma unroll
            for (int f = 0; f < 4; ++f) {
                bf16x8 vf = *(const bf16x8*)&Vl[(f * 16 + fr) * 64 + (((4 * m + fq) ^ f3) * 8)];
                Ot[f] = mfma16(vf, pb[m], Ot[f]);
            }
        __builtin_amdgcn_s_setprio(0);
        L += accS[0];

        asm volatile("s_waitcnt lgkmcnt(0)" ::: "memory");
        __builtin_amdgcn_s_barrier();   // all waves done reading before restage
    }

    // ---- epilogue: out[b][h*64+d][q], coalesced along q=fr
    float rcp = (L > 0.f) ? 1.f / L : 0.f;
    int q = row0 + fr;
#pragma unroll
    for (int f = 0; f < 4; ++f)
#pragma unroll
        for (int rr = 0; rr < 4; ++rr) {
            int d = f * 16 + fq * 4 + rr;
            out[((size_t)b * 512 + h * 64 + d) * 1024 + q] = Ot[f][rr] * rcp;
        }
}

extern "C" void kernel_launch(void* const* d_in, const int* in_sizes, int n_in,
                              void* d_out, int out_size, void* d_ws, size_t ws_size,
                              hipStream_t stream) {
    const float* q    = (const float*)d_in[0];
    const float* k    = (const float*)d_in[1];
    const float* Wq_v = (const float*)d_in[2];
    const float* Wq_g = (const float*)d_in[3];
    const float* bq   = (const float*)d_in[4];
    const float* Wk_v = (const float*)d_in[5];
    const float* Wk_g = (const float*)d_in[6];
    const float* bk   = (const float*)d_in[7];
    const float* Wv_v = (const float*)d_in[8];
    const float* Wv_g = (const float*)d_in[9];
    const float* bv   = (const float*)d_in[10];
    float* out = (float*)d_out;

    char* ws = (char*)d_ws;
    unsigned short* qT = (unsigned short*)(ws + 0);                  // [8][12][1024][32] bf16
    unsigned short* kT = (unsigned short*)(ws + 6291456);
    unsigned short* Wn = (unsigned short*)(ws + 12582912);           // [3][12][512][32] bf16
    unsigned short* Qp = (unsigned short*)(ws + 13762560);           // 8*1024*512 bf16
    unsigned short* Kp = (unsigned short*)(ws + 22151168);
    unsigned short* Vt = (unsigned short*)(ws + 30539776);           // [b][c][s]

    prep_kernel<<<dim3(32, 12, 17), dim3(256), 0, stream>>>(
        q, k, Wq_v, Wq_g, Wk_v, Wk_g, Wv_v, Wv_g, qT, kT, Wn);
    proj_gemm<<<dim3(8, 4, 24), dim3(256), 0, stream>>>(qT, kT, Wn, bq, bk, bv, Qp, Kp, Vt);
    attn_kernel<<<dim3(64, 16), dim3(256), 0, stream>>>(Qp, Kp, Vt, out);
}

// Round 22
// 53.525 us; speedup vs baseline: 1.0047x; 1.0047x over previous
//
#include <hip/hip_runtime.h>
#include <hip/hip_bf16.h>

typedef __attribute__((ext_vector_type(8))) __bf16 bf16x8;
typedef __attribute__((ext_vector_type(4))) float f32x4;

__device__ __forceinline__ f32x4 mfma16(bf16x8 a, bf16x8 b, f32x4 c) {
    return __builtin_amdgcn_mfma_f32_16x16x32_bf16(a, b, c, 0, 0, 0);
}

__device__ __forceinline__ unsigned short f2bf(float x) {
    union { float f; unsigned int u; } cv; cv.f = x;
    unsigned int r = cv.u + 0x7FFFu + ((cv.u >> 16) & 1u);
    return (unsigned short)(r >> 16);
}

__device__ __forceinline__ unsigned pack2(float a, float b) {
    return (unsigned)f2bf(a) | ((unsigned)f2bf(b) << 16);
}

__device__ __forceinline__ unsigned pk2(float a, float b) {
    float2 f2; f2.x = a; f2.y = b;
    __hip_bfloat162 h = __float22bfloat162_rn(f2);
    return *(unsigned*)&h;
}

__device__ __forceinline__ float fast_exp2(float x) {
    float r;
    asm("v_exp_f32 %0, %1" : "=v"(r) : "v"(x));
    return r;
}

// swap a[32:63] <-> b[0:31]   (operands must be distinct SSA values: R6 bug)
__device__ __forceinline__ void permswap32(unsigned &a, unsigned &b) {
    asm("v_permlane32_swap_b32 %0, %1" : "+v"(a), "+v"(b));
}
__device__ __forceinline__ void permswap16(unsigned &a, unsigned &b) {
    asm("v_permlane16_swap_b32 %0, %1" : "+v"(a), "+v"(b));
}

__device__ __forceinline__ void gload_lds16(const void* g, void* l) {
    __builtin_amdgcn_global_load_lds(
        (const __attribute__((address_space(1))) unsigned int*)g,
        (__attribute__((address_space(3))) unsigned int*)l, 16, 0, 0);
}

// ---------------- Kernel 1: fused weight-norm + q/k transpose ---------------
// Outputs K-CHUNKED layouts for coalesced GEMM staging:
//   qT/kT: [B][K/32][S][32]   Wn: [proj][K/32][512][32]
__global__ __launch_bounds__(256) void prep_kernel(
    const float* __restrict__ q, const float* __restrict__ k,
    const float* __restrict__ Wq_v, const float* __restrict__ Wq_g,
    const float* __restrict__ Wk_v, const float* __restrict__ Wk_g,
    const float* __restrict__ Wv_v, const float* __restrict__ Wv_g,
    unsigned short* __restrict__ qT, unsigned short* __restrict__ kT,
    unsigned short* __restrict__ Wn)
{
    __shared__ float tile[32][33];
    int z = blockIdx.z;
    int t = threadIdx.x;
    if (z == 16) {
        int w = t >> 6, lane = t & 63;
        int idx = (blockIdx.y * 32 + blockIdx.x) * 4 + w;   // 0..1535
        int proj = idx >> 9, o = idx & 511;
        const float* v = (proj == 0 ? Wq_v : proj == 1 ? Wk_v : Wv_v) + (size_t)o * 384;
        const float* g = (proj == 0 ? Wq_g : proj == 1 ? Wk_g : Wv_g);
        float vals[6];
        float ss = 0.f;
#pragma unroll
        for (int i = 0; i < 6; ++i) { vals[i] = v[lane + i * 64]; ss += vals[i] * vals[i]; }
#pragma unroll
        for (int off = 1; off < 64; off <<= 1) ss += __shfl_xor(ss, off, 64);
        float scale = g[o] * rsqrtf(ss);
        unsigned short* dst = Wn + (size_t)proj * 512 * 384;
#pragma unroll
        for (int i = 0; i < 6; ++i) {
            int c = lane + i * 64;
            dst[((size_t)(c >> 5) * 512 + o) * 32 + (c & 31)] = f2bf(vals[i] * scale);
        }
        return;
    }
    int tx = t & 31, ty = t >> 5;
    const float* src = (z < 8 ? q : k) + (size_t)(z & 7) * 384 * 1024;
    unsigned short* dst = (z < 8 ? qT : kT) + (size_t)(z & 7) * 1024 * 384;
    int c0 = blockIdx.y * 32, s0 = blockIdx.x * 32;
#pragma unroll
    for (int j = 0; j < 4; ++j)
        tile[ty + j * 8][tx] = src[(size_t)(c0 + ty + j * 8) * 1024 + s0 + tx];
    __syncthreads();
    int cp = tx & 15;
    int chunk = c0 >> 5;
#pragma unroll
    for (int j = 0; j < 2; ++j) {
        int ss = ty + (tx >> 4) * 8 + j * 16;
        *(unsigned*)&dst[((size_t)chunk * 1024 + s0 + ss) * 32 + 2 * cp] =
            pk2(tile[2 * cp][ss], tile[2 * cp + 1][ss]);
    }
}

// ---------------- Kernel 2: projection GEMM (R14 version, best measured) ----
// K-chunked inputs -> fully coalesced staging (4 x 1KB gloads per wave/step),
// double-buffered. proj==0 (Q) output PRE-SCALED by 1/sqrt(64)*log2(e).
__global__ __launch_bounds__(256) void proj_gemm(
    const unsigned short* __restrict__ qT, const unsigned short* __restrict__ kT,
    const unsigned short* __restrict__ Wn,
    const float* __restrict__ bq, const float* __restrict__ bk, const float* __restrict__ bv,
    unsigned short* __restrict__ Qp, unsigned short* __restrict__ Kp,
    unsigned short* __restrict__ Vt)
{
    __shared__ __align__(16) unsigned short pool[4][128 * 32];   // Asm[2] | Bsm[2]
    int zb = blockIdx.z; int proj = zb >> 3, b = zb & 7;
    const unsigned short* A = (proj == 0 ? qT : kT) + (size_t)b * 1024 * 384;
    const unsigned short* Bw = Wn + (size_t)proj * 512 * 384;
    const float* bias = proj == 0 ? bq : (proj == 1 ? bk : bv);
    int m0 = blockIdx.x * 128, n0 = blockIdx.y * 128;
    int t = threadIdx.x, w = t >> 6, lane = t & 63;
    int fr = lane & 15, fq = lane >> 4;
    int wm = (w >> 1) * 64, wn = (w & 1) * 64;

    f32x4 acc[4][4];
#pragma unroll
    for (int i = 0; i < 4; ++i)
#pragma unroll
        for (int j = 0; j < 4; ++j) acc[i][j] = (f32x4){0.f, 0.f, 0.f, 0.f};

    auto stageAB = [&](int k0, int bufi) {
        int ch = k0 >> 5;
        const unsigned short* ab = A + ((size_t)ch * 1024 + m0) * 32 + w * 1024 + lane * 8;
        const unsigned short* bb = Bw + ((size_t)ch * 512 + n0) * 32 + w * 1024 + lane * 8;
        gload_lds16(ab, &pool[bufi][w * 1024]);
        gload_lds16(ab + 512, &pool[bufi][w * 1024 + 512]);
        gload_lds16(bb, &pool[2 + bufi][w * 1024]);
        gload_lds16(bb + 512, &pool[2 + bufi][w * 1024 + 512]);
    };

    stageAB(0, 0);
    for (int ks = 0; ks < 12; ++ks) {
        if (ks < 11) {
            stageAB((ks + 1) * 32, (ks + 1) & 1);
            asm volatile("s_waitcnt vmcnt(4)" ::: "memory");
        } else {
            asm volatile("s_waitcnt vmcnt(0)" ::: "memory");
        }
        __builtin_amdgcn_s_barrier();
        int bi = ks & 1;
        bf16x8 af[4], bfr[4];
#pragma unroll
        for (int i = 0; i < 4; ++i)
            af[i] = *(const bf16x8*)&pool[bi][(wm + i * 16 + fr) * 32 + fq * 8];
#pragma unroll
        for (int i = 0; i < 4; ++i)
            bfr[i] = *(const bf16x8*)&pool[2 + bi][(wn + i * 16 + fr) * 32 + fq * 8];
#pragma unroll
        for (int mi = 0; mi < 4; ++mi)
#pragma unroll
            for (int ni = 0; ni < 4; ++ni)
                acc[mi][ni] = mfma16(af[mi], bfr[ni], acc[mi][ni]);
        asm volatile("s_waitcnt lgkmcnt(0)" ::: "memory");
        __builtin_amdgcn_s_barrier();
    }

    if (proj == 2) {
#pragma unroll
        for (int mi = 0; mi < 4; ++mi)
#pragma unroll
            for (int ni = 0; ni < 4; ++ni) {
                int c = n0 + wn + ni * 16 + fr;
                int s0 = m0 + wm + mi * 16 + fq * 4;
                float bc = bias[c];
                unsigned lo = pack2(acc[mi][ni][0] + bc, acc[mi][ni][1] + bc);
                unsigned hi = pack2(acc[mi][ni][2] + bc, acc[mi][ni][3] + bc);
                uint2 u; u.x = lo; u.y = hi;
                *(uint2*)&Vt[(((size_t)b * 512 + c) * 1024 + s0)] = u;
            }
    } else {
        unsigned short* Out = (proj == 0 ? Qp : Kp) + (size_t)b * 1024 * 512;
        float vscale = (proj == 0) ? 0.18033688011112043f : 1.0f;
        const int STR = 72;
        unsigned short* scr = &pool[0][0] + w * 2304;
#pragma unroll
        for (int p = 0; p < 2; ++p) {
#pragma unroll
            for (int mh = 0; mh < 2; ++mh) {
                int mi = p * 2 + mh;
#pragma unroll
                for (int ni = 0; ni < 4; ++ni) {
                    int c = n0 + wn + ni * 16 + fr;
                    float bc = bias[c];
#pragma unroll
                    for (int r = 0; r < 4; ++r)
                        scr[(mh * 16 + fq * 4 + r) * STR + ni * 16 + fr] =
                            f2bf((acc[mi][ni][r] + bc) * vscale);
                }
            }
            asm volatile("s_waitcnt lgkmcnt(0)" ::: "memory");
            int sp = lane >> 1, ch = (lane & 1) * 32;
            int s = m0 + wm + p * 32 + sp;
#pragma unroll
            for (int kk = 0; kk < 4; ++kk) {
                bf16x8 v = *(const bf16x8*)&scr[sp * STR + ch + 8 * kk];
                *(bf16x8*)&Out[(size_t)s * 512 + n0 + wn + ch + 8 * kk] = v;
            }
            asm volatile("s_waitcnt lgkmcnt(0)" ::: "memory");
        }
    }
}

// ---------------- Kernel 3: flash attention, KVBLK=64, single-buffer --------
// LDS 16KB -> 6 blocks/CU (24 waves/CU). Best measured attn configuration.
__global__ __launch_bounds__(256, 6) void attn_kernel(
    const unsigned short* __restrict__ Qp, const unsigned short* __restrict__ Kp,
    const unsigned short* __restrict__ Vt, float* __restrict__ out)
{
    __shared__ __align__(16) unsigned short Kl[64 * 64];   // [key][c], swizzled
    __shared__ __align__(16) unsigned short Vl[64 * 64];   // [d][key], swizzled
    int y = blockIdx.y;
    int qtile = y < 4 ? y : (y < 8 ? 19 - y : (y < 12 ? 15 - y : y - 4));
    int bh = blockIdx.x, b = bh >> 3, h = bh & 7;
    int tid = threadIdx.x, w = tid >> 6, lane = tid & 63;
    int fr = lane & 15, fq = lane >> 4;
    const unsigned short* Qb = Qp + ((size_t)b * 1024) * 512 + h * 64;
    const unsigned short* Kb = Kp + ((size_t)b * 1024) * 512 + h * 64;
    const unsigned short* VTb = Vt + ((size_t)b * 512 + h * 64) * 1024;
    int f3 = fr & 7;
    int sw = 8 * ((lane & 7) ^ (lane >> 3));      // stage pre-swizzle (shorts)

    union { unsigned u[4]; bf16x8 v; } ones;
#pragma unroll
    for (int i = 0; i < 4; ++i) ones.u[i] = 0x3F803F80u;   // bf16 1.0 pairs

    auto stage = [&](int kt) {
        int kbase = kt * 64;
#pragma unroll
        for (int i = 0; i < 2; ++i) {
            int r0 = w * 16 + i * 8;
            gload_lds16(Kb + (size_t)(kbase + r0 + (lane >> 3)) * 512 + sw,
                        &Kl[r0 * 64]);
        }
#pragma unroll
        for (int i = 0; i < 2; ++i) {
            int d0 = w * 16 + i * 8;
            gload_lds16(VTb + (size_t)(d0 + (lane >> 3)) * 1024 + kbase + sw,
                        &Vl[d0 * 64]);
        }
    };

    int row0 = qtile * 64 + w * 16;
    int nt = qtile + 1;                 // 64-key units
    int qrow = row0 + fr;

    bf16x8 qf0 = *(const bf16x8*)(Qb + (size_t)(row0 + fr) * 512 + fq * 8);
    bf16x8 qf1 = *(const bf16x8*)(Qb + (size_t)(row0 + fr) * 512 + 32 + fq * 8);

    f32x4 Ot[4];
#pragma unroll
    for (int f = 0; f < 4; ++f) Ot[f] = (f32x4){0.f, 0.f, 0.f, 0.f};
    float M = -128.f, L = 0.f;

    for (int kt = 0; kt < nt; ++kt) {
        int kbase = kt * 64;
        stage(kt);
        asm volatile("s_waitcnt vmcnt(0)" ::: "memory");
        __builtin_amdgcn_s_barrier();

        // ---- QK^T (swapped): S[kg] = D[key=kg*16+fq*4+r][q=fr], pre-scaled
        f32x4 S[4];
#pragma unroll
        for (int kg = 0; kg < 4; ++kg) {
            bf16x8 k0 = *(const bf16x8*)&Kl[(kg * 16 + fr) * 64 + ((fq ^ f3) * 8)];
            bf16x8 k1 = *(const bf16x8*)&Kl[(kg * 16 + fr) * 64 + (((4 + fq) ^ f3) * 8)];
            S[kg] = mfma16(k0, qf0, (f32x4){0.f, 0.f, 0.f, 0.f});
            S[kg] = mfma16(k1, qf1, S[kg]);
        }

        // ---- mask + online softmax (log2 domain, defer-max THR=8)
        float vmax = -3e38f;
#pragma unroll
        for (int kg = 0; kg < 4; ++kg)
#pragma unroll
            for (int r = 0; r < 4; ++r) {
                int key = kbase + kg * 16 + fq * 4 + r;
                float sv = (key < qrow) ? S[kg][r] : -3e38f;
                S[kg][r] = sv;
                vmax = fmaxf(vmax, sv);
            }
        vmax = fmaxf(vmax, __shfl_xor(vmax, 16, 64));
        vmax = fmaxf(vmax, __shfl_xor(vmax, 32, 64));
        if (__any(vmax > M + 8.f)) {
            float Mn = fmaxf(M, vmax);
            float al = fast_exp2(M - Mn);
            L *= al;
            M = Mn;
#pragma unroll
            for (int f = 0; f < 4; ++f) {
                Ot[f][0] *= al; Ot[f][1] *= al; Ot[f][2] *= al; Ot[f][3] *= al;
            }
        }
#pragma unroll
        for (int kg = 0; kg < 4; ++kg)
#pragma unroll
            for (int r = 0; r < 4; ++r)
                S[kg][r] = fast_exp2(S[kg][r] - M);   // masked -> 0

        // ---- in-register P -> B-frags (2 frags of 32 keys)
        bf16x8 pb[2];
#pragma unroll
        for (int m = 0; m < 2; ++m) {
            unsigned A0 = pk2(S[2 * m][0], S[2 * m][1]);
            unsigned A1 = pk2(S[2 * m][2], S[2 * m][3]);
            unsigned B0 = pk2(S[2 * m + 1][0], S[2 * m + 1][1]);
            unsigned B1 = pk2(S[2 * m + 1][2], S[2 * m + 1][3]);
            permswap32(A0, B0); permswap16(A0, B0);
            permswap32(A1, B1); permswap16(A1, B1);
            union { unsigned u[4]; bf16x8 v; } pu;
            pu.u[0] = A0; pu.u[1] = A1; pu.u[2] = B0; pu.u[3] = B1;
            pb[m] = pu.v;
        }

        // ---- denominator via ones-MFMA: every D row = sum_k P[k][q]
        f32x4 accS = (f32x4){0.f, 0.f, 0.f, 0.f};
        accS = mfma16(ones.v, pb[0], accS);
        accS = mfma16(ones.v, pb[1], accS);
        L += accS[0];

        // ---- PV: O^T += V^T x P
#pragma unroll
        for (int m = 0; m < 2; ++m)
#pragma unroll
            for (int f = 0; f < 4; ++f) {
                bf16x8 vf = *(const bf16x8*)&Vl[(f * 16 + fr) * 64 + (((4 * m + fq) ^ f3) * 8)];
                Ot[f] = mfma16(vf, pb[m], Ot[f]);
            }

        asm volatile("s_waitcnt lgkmcnt(0)" ::: "memory");
        __builtin_amdgcn_s_barrier();   // all waves done reading before restage
    }

    // ---- epilogue: out[b][h*64+d][q], coalesced along q=fr
    float rcp = (L > 0.f) ? 1.f / L : 0.f;
    int q = row0 + fr;
#pragma unroll
    for (int f = 0; f < 4; ++f)
#pragma unroll
        for (int rr = 0; rr < 4; ++rr) {
            int d = f * 16 + fq * 4 + rr;
            out[((size_t)b * 512 + h * 64 + d) * 1024 + q] = Ot[f][rr] * rcp;
        }
}

extern "C" void kernel_launch(void* const* d_in, const int* in_sizes, int n_in,
                              void* d_out, int out_size, void* d_ws, size_t ws_size,
                              hipStream_t stream) {
    const float* q    = (const float*)d_in[0];
    const float* k    = (const float*)d_in[1];
    const float* Wq_v = (const float*)d_in[2];
    const float* Wq_g = (const float*)d_in[3];
    const float* bq   = (const float*)d_in[4];
    const float* Wk_v = (const float*)d_in[5];
    const float* Wk_g = (const float*)d_in[6];
    const float* bk   = (const float*)d_in[7];
    const float* Wv_v = (const float*)d_in[8];
    const float* Wv_g = (const float*)d_in[9];
    const float* bv   = (const float*)d_in[10];
    float* out = (float*)d_out;

    char* ws = (char*)d_ws;
    unsigned short* qT = (unsigned short*)(ws + 0);                  // [8][12][1024][32] bf16
    unsigned short* kT = (unsigned short*)(ws + 6291456);
    unsigned short* Wn = (unsigned short*)(ws + 12582912);           // [3][12][512][32] bf16
    unsigned short* Qp = (unsigned short*)(ws + 13762560);           // 8*1024*512 bf16
    unsigned short* Kp = (unsigned short*)(ws + 22151168);
    unsigned short* Vt = (unsigned short*)(ws + 30539776);           // [b][c][s]

    prep_kernel<<<dim3(32, 12, 17), dim3(256), 0, stream>>>(
        q, k, Wq_v, Wq_g, Wk_v, Wk_g, Wv_v, Wv_g, qT, kT, Wn);
    proj_gemm<<<dim3(8, 4, 24), dim3(256), 0, stream>>>(qT, kT, Wn, bq, bk, bv, Qp, Kp, Vt);
    attn_kernel<<<dim3(64, 16), dim3(256), 0, stream>>>(Qp, Kp, Vt, out);
}